// Round 3
// baseline (2536.502 us; speedup 1.0000x reference)
//
#include <hip/hip_runtime.h>

// ---- problem constants ----
#define NB    8
#define HIN   384
#define WIN   384
#define HOUT  192
#define WOUT  192
#define HW_IN (HIN * WIN)          // 147456
#define PLANE (HOUT * WOUT)        // 36864
#define CNT_BN (NB * HOUT * WOUT)  // 294912

// ---- workspace layout (float offsets) ----
#define WS_MEANS 0       // 512:   per-(n,c) spatial SUMS (scaled in k_agg), n*64+c
#define WS_AGGV  512     // 24576: aggregated vert weights [n][c][t][o]
#define WS_AGGH  25088   // 24576: aggregated horz weights [n][c][t][o]
#define WS_SQW   49664   // 36864: sq weights transposed [c][ky][kx][oc]
#define WS_STATS 86528   // 128:   sum_v[32] sumsq_v[32] sum_h[32] sumsq_h[32]
#define WS_BN    86656   // 128:   scale_v[32] shift_v[32] scale_h[32] shift_h[32]

// ---------------- zero means + stats ----------------
__global__ void k_zero(float* __restrict__ ws) {
    for (int i = threadIdx.x; i < 512; i += 256) ws[WS_MEANS + i] = 0.f;
    if (threadIdx.x < 128) ws[WS_STATS + threadIdx.x] = 0.f;
}

// ---------------- per-(n,c) spatial sum (4 partial blocks per plane) ----------------
__global__ __launch_bounds__(256) void k_means(const float* __restrict__ x,
                                               float* __restrict__ ws) {
    int bc = blockIdx.x;    // n*64 + c, 512
    int part = blockIdx.y;  // 0..3
    const float4* p = (const float4*)(x + (size_t)bc * HW_IN) + part * (HW_IN / 16);
    float s = 0.f;
    for (int i = threadIdx.x; i < HW_IN / 16; i += 256) {
        float4 v = p[i];
        s += (v.x + v.y) + (v.z + v.w);
    }
    __shared__ float red[256];
    red[threadIdx.x] = s;
    __syncthreads();
    for (int off = 128; off > 0; off >>= 1) {
        if ((int)threadIdx.x < off) red[threadIdx.x] += red[threadIdx.x + off];
        __syncthreads();
    }
    if (threadIdx.x == 0) atomicAdd(&ws[WS_MEANS + bc], red[0]);
}

// ---------------- attention + expert aggregation ----------------
__global__ void k_agg(const float* __restrict__ aw_v, const float* __restrict__ ab_v,
                      const float* __restrict__ wv,
                      const float* __restrict__ aw_h, const float* __restrict__ ab_h,
                      const float* __restrict__ wh, float* __restrict__ ws) {
    int n = blockIdx.x;  // 8 blocks
    __shared__ float att[8];  // [0..3] vert, [4..7] horz
    if (threadIdx.x < 8) {
        int k = threadIdx.x & 3;
        int hsel = threadIdx.x >> 2;
        const float* m = ws + WS_MEANS + n * 64 + hsel * 32;  // raw sums
        const float* aw = hsel ? aw_h : aw_v;
        const float* ab = hsel ? ab_h : ab_v;
        float dot = 0.f;
        for (int c = 0; c < 32; c++) dot += m[c] * aw[k * 32 + c];
        float z = ab[k] + dot * (1.0f / HW_IN);
        att[threadIdx.x] = 1.0f / (1.0f + expf(-z));
    }
    __syncthreads();
    // dst [c][t][o]: i = (c*3+t)*32 + o ; src [k][o][c][t] = (k*32+o)*96 + (c*3+t)
    for (int i = threadIdx.x; i < 3072; i += 256) {
        int o = i & 31;
        int r = i >> 5;  // c*3 + t
        float sv = 0.f, sh = 0.f;
#pragma unroll
        for (int k = 0; k < 4; k++) {
            sv += att[k]     * wv[(k * 32 + o) * 96 + r];
            sh += att[4 + k] * wh[(k * 32 + o) * 96 + r];
        }
        ws[WS_AGGV + n * 3072 + i] = sv;
        ws[WS_AGGH + n * 3072 + i] = sh;
    }
}

// ---------------- sq weight transpose: [oc][c][ky][kx] -> [c][ky][kx][oc] ----------------
__global__ void k_cvtw(const float* __restrict__ sq_w, float* __restrict__ ws) {
    int i = blockIdx.x * 256 + threadIdx.x;  // 36864 total, grid 144
    int oc = i & 63;
    int r = i >> 6;           // c*9 + (ky*3+kx)
    int c = r / 9, q = r % 9;
    ws[WS_SQW + i] = sq_w[(oc * 64 + c) * 9 + q];
}

// ---------------- square 3x3/s2 conv: 64 oc x 2 pixels per thread ----------------
// block = 192 thr: i = tid%96 (out cols 2i,2i+1), r = tid/96 (row pair)
__global__ __launch_bounds__(192) void k_sq(const float* __restrict__ x,
                                            const float* __restrict__ sq_b,
                                            const float* __restrict__ ws,
                                            float* __restrict__ out) {
    int tid = threadIdx.x;
    int i = tid % 96;
    int r = tid / 96;
    int yo = blockIdx.x * 2 + r;   // grid.x = 96
    int n  = blockIdx.y;           // 0..7
    const float* wp = ws + WS_SQW;
    float acc0[64], acc1[64];
#pragma unroll
    for (int j = 0; j < 64; j++) { acc0[j] = sq_b[j]; acc1[j] = acc0[j]; }
    const float* xb = x + (size_t)n * 64 * HW_IN;
    int c4 = 4 * i;
    int iy0 = 2 * yo - 1;
    for (int c = 0; c < 64; c++) {
        const float* xc = xb + (size_t)c * HW_IN;
        float4 vv[3];
        float sm[3];
#pragma unroll
        for (int ky = 0; ky < 3; ky++) {
            int iy = iy0 + ky;   // per-lane (r varies within wave 1)
            const float* row = xc + (size_t)iy * WIN + c4;
            if (iy >= 0) {
                vv[ky] = *(const float4*)row;
                sm[ky] = (i > 0) ? row[-1] : 0.f;
            } else {
                vv[ky] = make_float4(0.f, 0.f, 0.f, 0.f);
                sm[ky] = 0.f;
            }
        }
        const float* wc = wp + c * 576;   // [ky][kx][64] — wave-uniform -> s_load
#pragma unroll
        for (int ky = 0; ky < 3; ky++) {
            const float* w0 = wc + ky * 192;
            float s = sm[ky];
            float4 v = vv[ky];
#pragma unroll
            for (int j = 0; j < 64; j++) {
                float wa = w0[j], wb = w0[64 + j], wcv = w0[128 + j];
                acc0[j] += s   * wa + v.x * wb + v.y * wcv;
                acc1[j] += v.y * wa + v.z * wb + v.w * wcv;
            }
        }
    }
    size_t ob = (size_t)n * 128 * PLANE + (size_t)yo * WOUT + 2 * i;
#pragma unroll
    for (int j = 0; j < 64; j++) {
        int co = ((j & 15) << 3) | (j >> 4);   // channel shuffle g=8 (ci = j)
        *(float2*)(out + ob + (size_t)co * PLANE) = make_float2(acc0[j], acc1[j]);
    }
}

// ---------------- vertical CondConv 3x1 pad(1,0): 32 oc x 2 pixels per thread ----------
__global__ __launch_bounds__(192) void k_vert(const float* __restrict__ x,
                                              const float* __restrict__ ws,
                                              float* __restrict__ out) {
    int tid = threadIdx.x;
    int i = tid % 96;
    int r = tid / 96;
    int yo = blockIdx.x * 2 + r;   // grid.x = 96
    int n  = blockIdx.y;
    const float* wn = ws + WS_AGGV + n * 3072;
    float acc0[32], acc1[32];
#pragma unroll
    for (int j = 0; j < 32; j++) { acc0[j] = 0.f; acc1[j] = 0.f; }
    const float* xb = x + (size_t)n * 64 * HW_IN;   // channels 0..31
    int c4 = 4 * i;
    int iy0 = 2 * yo - 1;
#pragma unroll 2
    for (int c = 0; c < 32; c++) {
        const float* xc = xb + (size_t)c * HW_IN;
        float4 vv[3];
#pragma unroll
        for (int t = 0; t < 3; t++) {
            int iy = iy0 + t;
            const float* row = xc + (size_t)iy * WIN + c4;
            vv[t] = (iy >= 0) ? *(const float4*)row : make_float4(0.f, 0.f, 0.f, 0.f);
        }
#pragma unroll
        for (int t = 0; t < 3; t++) {
            const float* wr = wn + (c * 3 + t) * 32;   // uniform -> s_load
            float va = vv[t].x, vb = vv[t].z;          // cols 4i, 4i+2
#pragma unroll
            for (int j = 0; j < 32; j++) {
                float w = wr[j];
                acc0[j] += va * w;
                acc1[j] += vb * w;
            }
        }
    }
    size_t ob = (size_t)n * 128 * PLANE + (size_t)yo * WOUT + 2 * i;
#pragma unroll
    for (int j = 0; j < 32; j++) {
        int ci = 64 + j;
        int co = ((ci & 15) << 3) | (ci >> 4);
        *(float2*)(out + ob + (size_t)co * PLANE) = make_float2(acc0[j], acc1[j]);
    }
}

// ---------------- horizontal CondConv 1x3 pad(0,1): 32 oc x 2 pixels per thread --------
__global__ __launch_bounds__(192) void k_horz(const float* __restrict__ x,
                                              const float* __restrict__ ws,
                                              float* __restrict__ out) {
    int tid = threadIdx.x;
    int i = tid % 96;
    int r = tid / 96;
    int yo = blockIdx.x * 2 + r;   // grid.x = 96
    int n  = blockIdx.y;
    const float* wn = ws + WS_AGGH + n * 3072;
    float acc0[32], acc1[32];
#pragma unroll
    for (int j = 0; j < 32; j++) { acc0[j] = 0.f; acc1[j] = 0.f; }
    const float* xb = x + ((size_t)n * 64 + 32) * HW_IN;   // channels 32..63
    int c4 = 4 * i;
#pragma unroll 2
    for (int c = 0; c < 32; c++) {
        const float* row = xb + (size_t)c * HW_IN + (size_t)(2 * yo) * WIN + c4;
        float4 v = *(const float4*)row;
        float vm1 = (i > 0) ? row[-1] : 0.f;
        const float* wr = wn + c * 96;                     // uniform -> s_load
#pragma unroll
        for (int j = 0; j < 32; j++) {
            float w0 = wr[j], w1 = wr[32 + j], w2 = wr[64 + j];
            acc0[j] += vm1 * w0 + v.x * w1 + v.y * w2;
            acc1[j] += v.y * w0 + v.z * w1 + v.w * w2;
        }
    }
    size_t ob = (size_t)n * 128 * PLANE + (size_t)yo * WOUT + 2 * i;
#pragma unroll
    for (int j = 0; j < 32; j++) {
        int ci = 96 + j;
        int co = ((ci & 15) << 3) | (ci >> 4);
        *(float2*)(out + ob + (size_t)co * PLANE) = make_float2(acc0[j], acc1[j]);
    }
}

// ---------------- BN stats over raw conv output (v/h channels of out) ----------------
__global__ __launch_bounds__(256) void k_stats(const float* __restrict__ out,
                                               float* __restrict__ ws) {
    int sch = blockIdx.x;   // 0..63: 0..31 vert oc, 32..63 horz oc
    int n = blockIdx.y;     // 0..7
    int vh = sch >> 5, oc = sch & 31;
    int ci = 64 + sch;
    int co = ((ci & 15) << 3) | (ci >> 4);
    const float4* p = (const float4*)(out + (size_t)(n * 128 + co) * PLANE);
    float s = 0.f, q = 0.f;
    for (int i = threadIdx.x; i < PLANE / 4; i += 256) {
        float4 v = p[i];
        s += (v.x + v.y) + (v.z + v.w);
        q += (v.x * v.x + v.y * v.y) + (v.z * v.z + v.w * v.w);
    }
    __shared__ float rs[256], rq[256];
    rs[threadIdx.x] = s; rq[threadIdx.x] = q;
    __syncthreads();
    for (int off = 128; off > 0; off >>= 1) {
        if ((int)threadIdx.x < off) {
            rs[threadIdx.x] += rs[threadIdx.x + off];
            rq[threadIdx.x] += rq[threadIdx.x + off];
        }
        __syncthreads();
    }
    if (threadIdx.x == 0) {
        atomicAdd(&ws[WS_STATS + vh * 64 + oc], rs[0]);
        atomicAdd(&ws[WS_STATS + vh * 64 + 32 + oc], rq[0]);
    }
}

// ---------------- BN finalize ----------------
__global__ void k_bnfin(const float* __restrict__ gv, const float* __restrict__ bv,
                        const float* __restrict__ gh, const float* __restrict__ bh,
                        float* __restrict__ ws) {
    int t = threadIdx.x;
    if (t >= 64) return;
    int vh = t >> 5;  // 0 = vert, 1 = horz
    int c = t & 31;
    const float* st = ws + WS_STATS + vh * 64;
    float mean = st[c] * (1.0f / CNT_BN);
    float var = st[32 + c] * (1.0f / CNT_BN) - mean * mean;
    float g = vh ? gh[c] : gv[c];
    float b = vh ? bh[c] : bv[c];
    float scale = g * rsqrtf(var + 1e-5f);
    float* bn = ws + WS_BN + vh * 64;
    bn[c] = scale;
    bn[32 + c] = b - mean * scale;
}

// ---------------- BN apply in-place on v/h channels of out ----------------
__global__ __launch_bounds__(256) void k_apply(float* __restrict__ out,
                                               const float* __restrict__ ws) {
    int sch = blockIdx.x;   // 0..63
    int n = blockIdx.y;     // 0..7
    int vh = sch >> 5, oc = sch & 31;
    int ci = 64 + sch;
    int co = ((ci & 15) << 3) | (ci >> 4);
    const float* bn = ws + WS_BN + vh * 64;
    float scale = bn[oc], shift = bn[32 + oc];
    float4* p = (float4*)(out + (size_t)(n * 128 + co) * PLANE);
    for (int i = threadIdx.x; i < PLANE / 4; i += 256) {
        float4 v = p[i];
        v.x = v.x * scale + shift;
        v.y = v.y * scale + shift;
        v.z = v.z * scale + shift;
        v.w = v.w * scale + shift;
        p[i] = v;
    }
}

extern "C" void kernel_launch(void* const* d_in, const int* in_sizes, int n_in,
                              void* d_out, int out_size, void* d_ws, size_t ws_size,
                              hipStream_t stream) {
    const float* x    = (const float*)d_in[0];
    const float* sq_w = (const float*)d_in[1];
    const float* sq_b = (const float*)d_in[2];
    const float* aw_v = (const float*)d_in[3];
    const float* ab_v = (const float*)d_in[4];
    const float* w_v  = (const float*)d_in[5];
    const float* gv   = (const float*)d_in[6];
    const float* bv   = (const float*)d_in[7];
    const float* aw_h = (const float*)d_in[8];
    const float* ab_h = (const float*)d_in[9];
    const float* w_h  = (const float*)d_in[10];
    const float* gh   = (const float*)d_in[11];
    const float* bh   = (const float*)d_in[12];
    float* out = (float*)d_out;
    float* ws = (float*)d_ws;

    hipLaunchKernelGGL(k_zero, dim3(1), dim3(256), 0, stream, ws);
    hipLaunchKernelGGL(k_means, dim3(512, 4), dim3(256), 0, stream, x, ws);
    hipLaunchKernelGGL(k_agg, dim3(8), dim3(256), 0, stream,
                       aw_v, ab_v, w_v, aw_h, ab_h, w_h, ws);
    hipLaunchKernelGGL(k_cvtw, dim3(144), dim3(256), 0, stream, sq_w, ws);
    hipLaunchKernelGGL(k_vert, dim3(96, 8), dim3(192), 0, stream, x, ws, out);
    hipLaunchKernelGGL(k_horz, dim3(96, 8), dim3(192), 0, stream, x, ws, out);
    hipLaunchKernelGGL(k_stats, dim3(64, 8), dim3(256), 0, stream, out, ws);
    hipLaunchKernelGGL(k_bnfin, dim3(1), dim3(64), 0, stream, gv, bv, gh, bh, ws);
    hipLaunchKernelGGL(k_apply, dim3(64, 8), dim3(256), 0, stream, out, ws);
    hipLaunchKernelGGL(k_sq, dim3(96, 8), dim3(192), 0, stream, x, sq_b, ws, out);
}

// Round 4
// 2133.308 us; speedup vs baseline: 1.1890x; 1.1890x over previous
//
#include <hip/hip_runtime.h>

// ---- problem constants ----
#define NB    8
#define HIN   384
#define WIN   384
#define HOUT  192
#define WOUT  192
#define HW_IN (HIN * WIN)          // 147456
#define PLANE (HOUT * WOUT)        // 36864
#define CNT_BN (NB * HOUT * WOUT)  // 294912

// ---- workspace layout (float offsets) ----
#define WS_MEANS 0       // 512:   per-(n,c) spatial SUMS (scaled in k_agg), n*64+c
#define WS_AGGV  512     // 24576: aggregated vert weights [n][c][t][o]
#define WS_AGGH  25088   // 24576: aggregated horz weights [n][c][t][o]
#define WS_SQW   49664   // 36864: sq weights transposed [c][ky][kx][oc]
#define WS_STATS 86528   // 128:   sum_v[32] sumsq_v[32] sum_h[32] sumsq_h[32]
#define WS_BN    86656   // 128:   scale_v[32] shift_v[32] scale_h[32] shift_h[32]

// ---------------- zero means + stats ----------------
__global__ void k_zero(float* __restrict__ ws) {
    for (int i = threadIdx.x; i < 512; i += 256) ws[WS_MEANS + i] = 0.f;
    if (threadIdx.x < 128) ws[WS_STATS + threadIdx.x] = 0.f;
}

// ---------------- per-(n,c) spatial sum (4 partial blocks per plane) ----------------
__global__ __launch_bounds__(256) void k_means(const float* __restrict__ x,
                                               float* __restrict__ ws) {
    int bc = blockIdx.x;    // n*64 + c, 512
    int part = blockIdx.y;  // 0..3
    const float4* p = (const float4*)(x + (size_t)bc * HW_IN) + part * (HW_IN / 16);
    float s = 0.f;
    for (int i = threadIdx.x; i < HW_IN / 16; i += 256) {
        float4 v = p[i];
        s += (v.x + v.y) + (v.z + v.w);
    }
    __shared__ float red[256];
    red[threadIdx.x] = s;
    __syncthreads();
    for (int off = 128; off > 0; off >>= 1) {
        if ((int)threadIdx.x < off) red[threadIdx.x] += red[threadIdx.x + off];
        __syncthreads();
    }
    if (threadIdx.x == 0) atomicAdd(&ws[WS_MEANS + bc], red[0]);
}

// ---------------- attention + expert aggregation ----------------
__global__ void k_agg(const float* __restrict__ aw_v, const float* __restrict__ ab_v,
                      const float* __restrict__ wv,
                      const float* __restrict__ aw_h, const float* __restrict__ ab_h,
                      const float* __restrict__ wh, float* __restrict__ ws) {
    int n = blockIdx.x;  // 8 blocks
    __shared__ float att[8];  // [0..3] vert, [4..7] horz
    if (threadIdx.x < 8) {
        int k = threadIdx.x & 3;
        int hsel = threadIdx.x >> 2;
        const float* m = ws + WS_MEANS + n * 64 + hsel * 32;  // raw sums
        const float* aw = hsel ? aw_h : aw_v;
        const float* ab = hsel ? ab_h : ab_v;
        float dot = 0.f;
        for (int c = 0; c < 32; c++) dot += m[c] * aw[k * 32 + c];
        float z = ab[k] + dot * (1.0f / HW_IN);
        att[threadIdx.x] = 1.0f / (1.0f + expf(-z));
    }
    __syncthreads();
    // dst [c][t][o]: i = (c*3+t)*32 + o ; src [k][o][c][t] = (k*32+o)*96 + (c*3+t)
    for (int i = threadIdx.x; i < 3072; i += 256) {
        int o = i & 31;
        int r = i >> 5;  // c*3 + t
        float sv = 0.f, sh = 0.f;
#pragma unroll
        for (int k = 0; k < 4; k++) {
            sv += att[k]     * wv[(k * 32 + o) * 96 + r];
            sh += att[4 + k] * wh[(k * 32 + o) * 96 + r];
        }
        ws[WS_AGGV + n * 3072 + i] = sv;
        ws[WS_AGGH + n * 3072 + i] = sh;
    }
}

// ---------------- sq weight transpose: [oc][c][ky][kx] -> [c][ky][kx][oc] ----------------
__global__ void k_cvtw(const float* __restrict__ sq_w, float* __restrict__ ws) {
    int i = blockIdx.x * 256 + threadIdx.x;  // 36864 total, grid 144
    int oc = i & 63;
    int r = i >> 6;           // c*9 + (ky*3+kx)
    int c = r / 9, q = r % 9;
    ws[WS_SQW + i] = sq_w[(oc * 64 + c) * 9 + q];
}

// ---------------- square 3x3/s2 conv: 32 oc (ocg half) x 2 pixels per thread ----------
// block = 192 thr: i = tid%96 (out cols 2i,2i+1), r = tid/96 (row pair)
// grid = (ocg=2, rowpair=96, n=8): ocg fastest so both halves share x in L2/L3
__global__ __launch_bounds__(192) void k_sq(const float* __restrict__ x,
                                            const float* __restrict__ sq_b,
                                            const float* __restrict__ ws,
                                            float* __restrict__ out) {
    int tid = threadIdx.x;
    int i = tid % 96;
    int r = tid / 96;
    int ocg = blockIdx.x;          // 0..1
    int yo = blockIdx.y * 2 + r;   // 0..191
    int n  = blockIdx.z;           // 0..7
    const float* wp = ws + WS_SQW + ocg * 32;  // [c][ky][kx][64], take 32-slice
    float acc0[32], acc1[32];
#pragma unroll
    for (int j = 0; j < 32; j++) { acc0[j] = sq_b[ocg * 32 + j]; acc1[j] = acc0[j]; }
    const float* xb = x + (size_t)n * 64 * HW_IN;
    int c4 = 4 * i;
    int iy0 = 2 * yo - 1;
    for (int c = 0; c < 64; c++) {
        const float* xc = xb + (size_t)c * HW_IN;
        float4 vv[3];
        float sm[3];
#pragma unroll
        for (int ky = 0; ky < 3; ky++) {
            int iy = iy0 + ky;
            const float* row = xc + (size_t)iy * WIN + c4;
            if (iy >= 0) {
                vv[ky] = *(const float4*)row;
                sm[ky] = (i > 0) ? row[-1] : 0.f;
            } else {
                vv[ky] = make_float4(0.f, 0.f, 0.f, 0.f);
                sm[ky] = 0.f;
            }
        }
        const float* wc = wp + c * 576;   // wave-uniform -> s_load
#pragma unroll
        for (int ky = 0; ky < 3; ky++) {
            const float* w0 = wc + ky * 192;
            float s = sm[ky];
            float4 v = vv[ky];
#pragma unroll
            for (int j = 0; j < 32; j++) {
                float wa = w0[j], wb = w0[64 + j], wcv = w0[128 + j];
                acc0[j] += s   * wa + v.x * wb + v.y * wcv;
                acc1[j] += v.y * wa + v.z * wb + v.w * wcv;
            }
        }
    }
    size_t ob = (size_t)n * 128 * PLANE + (size_t)yo * WOUT + 2 * i;
#pragma unroll
    for (int j = 0; j < 32; j++) {
        int ci = ocg * 32 + j;
        int co = ((ci & 15) << 3) | (ci >> 4);   // channel shuffle g=8
        *(float2*)(out + ob + (size_t)co * PLANE) = make_float2(acc0[j], acc1[j]);
    }
}

// ---------------- vertical CondConv 3x1 pad(1,0): 32 oc x 2 px, LDS weights ----------
__global__ __launch_bounds__(192) void k_vert(const float* __restrict__ x,
                                              const float* __restrict__ ws,
                                              float* __restrict__ out) {
    __shared__ float4 wl4[768];   // 3072 floats = this n's aggregated weights
    int tid = threadIdx.x;
    int i = tid % 96;
    int r = tid / 96;
    int yo = blockIdx.x * 2 + r;   // grid.x = 96
    int n  = blockIdx.y;
    const float4* src = (const float4*)(ws + WS_AGGV + n * 3072);
#pragma unroll
    for (int t = 0; t < 4; t++) wl4[tid + t * 192] = src[tid + t * 192];
    __syncthreads();
    const float* wl = (const float*)wl4;
    float acc0[32], acc1[32];
#pragma unroll
    for (int j = 0; j < 32; j++) { acc0[j] = 0.f; acc1[j] = 0.f; }
    const float* xb = x + (size_t)n * 64 * HW_IN;   // channels 0..31
    int c4 = 4 * i;
    int iy0 = 2 * yo - 1;
#pragma unroll 2
    for (int c = 0; c < 32; c++) {
        const float* xc = xb + (size_t)c * HW_IN;
        float4 vv[3];
#pragma unroll
        for (int t = 0; t < 3; t++) {
            int iy = iy0 + t;
            const float* row = xc + (size_t)iy * WIN + c4;
            vv[t] = (iy >= 0) ? *(const float4*)row : make_float4(0.f, 0.f, 0.f, 0.f);
        }
#pragma unroll
        for (int t = 0; t < 3; t++) {
            const float* wr = wl + (c * 3 + t) * 32;   // ds_read broadcast
            float va = vv[t].x, vb = vv[t].z;          // cols 4i, 4i+2
#pragma unroll
            for (int j = 0; j < 32; j++) {
                float w = wr[j];
                acc0[j] += va * w;
                acc1[j] += vb * w;
            }
        }
    }
    size_t ob = (size_t)n * 128 * PLANE + (size_t)yo * WOUT + 2 * i;
#pragma unroll
    for (int j = 0; j < 32; j++) {
        int ci = 64 + j;
        int co = ((ci & 15) << 3) | (ci >> 4);
        *(float2*)(out + ob + (size_t)co * PLANE) = make_float2(acc0[j], acc1[j]);
    }
}

// ---------------- horizontal CondConv 1x3 pad(0,1): 32 oc x 2 px, LDS weights --------
__global__ __launch_bounds__(192) void k_horz(const float* __restrict__ x,
                                              const float* __restrict__ ws,
                                              float* __restrict__ out) {
    __shared__ float4 wl4[768];
    int tid = threadIdx.x;
    int i = tid % 96;
    int r = tid / 96;
    int yo = blockIdx.x * 2 + r;   // grid.x = 96
    int n  = blockIdx.y;
    const float4* src = (const float4*)(ws + WS_AGGH + n * 3072);
#pragma unroll
    for (int t = 0; t < 4; t++) wl4[tid + t * 192] = src[tid + t * 192];
    __syncthreads();
    const float* wl = (const float*)wl4;
    float acc0[32], acc1[32];
#pragma unroll
    for (int j = 0; j < 32; j++) { acc0[j] = 0.f; acc1[j] = 0.f; }
    const float* xb = x + ((size_t)n * 64 + 32) * HW_IN;   // channels 32..63
    int c4 = 4 * i;
#pragma unroll 2
    for (int c = 0; c < 32; c++) {
        const float* row = xb + (size_t)c * HW_IN + (size_t)(2 * yo) * WIN + c4;
        float4 v = *(const float4*)row;
        float vm1 = (i > 0) ? row[-1] : 0.f;
        const float* wr = wl + c * 96;                     // ds_read broadcast
#pragma unroll
        for (int j = 0; j < 32; j++) {
            float w0 = wr[j], w1 = wr[32 + j], w2 = wr[64 + j];
            acc0[j] += vm1 * w0 + v.x * w1 + v.y * w2;
            acc1[j] += v.y * w0 + v.z * w1 + v.w * w2;
        }
    }
    size_t ob = (size_t)n * 128 * PLANE + (size_t)yo * WOUT + 2 * i;
#pragma unroll
    for (int j = 0; j < 32; j++) {
        int ci = 96 + j;
        int co = ((ci & 15) << 3) | (ci >> 4);
        *(float2*)(out + ob + (size_t)co * PLANE) = make_float2(acc0[j], acc1[j]);
    }
}

// ---------------- BN stats over raw conv output (v/h channels of out) ----------------
__global__ __launch_bounds__(256) void k_stats(const float* __restrict__ out,
                                               float* __restrict__ ws) {
    int sch = blockIdx.x;   // 0..63: 0..31 vert oc, 32..63 horz oc
    int n = blockIdx.y;     // 0..7
    int vh = sch >> 5, oc = sch & 31;
    int ci = 64 + sch;
    int co = ((ci & 15) << 3) | (ci >> 4);
    const float4* p = (const float4*)(out + (size_t)(n * 128 + co) * PLANE);
    float s = 0.f, q = 0.f;
    for (int i = threadIdx.x; i < PLANE / 4; i += 256) {
        float4 v = p[i];
        s += (v.x + v.y) + (v.z + v.w);
        q += (v.x * v.x + v.y * v.y) + (v.z * v.z + v.w * v.w);
    }
    __shared__ float rs[256], rq[256];
    rs[threadIdx.x] = s; rq[threadIdx.x] = q;
    __syncthreads();
    for (int off = 128; off > 0; off >>= 1) {
        if ((int)threadIdx.x < off) {
            rs[threadIdx.x] += rs[threadIdx.x + off];
            rq[threadIdx.x] += rq[threadIdx.x + off];
        }
        __syncthreads();
    }
    if (threadIdx.x == 0) {
        atomicAdd(&ws[WS_STATS + vh * 64 + oc], rs[0]);
        atomicAdd(&ws[WS_STATS + vh * 64 + 32 + oc], rq[0]);
    }
}

// ---------------- BN finalize ----------------
__global__ void k_bnfin(const float* __restrict__ gv, const float* __restrict__ bv,
                        const float* __restrict__ gh, const float* __restrict__ bh,
                        float* __restrict__ ws) {
    int t = threadIdx.x;
    if (t >= 64) return;
    int vh = t >> 5;  // 0 = vert, 1 = horz
    int c = t & 31;
    const float* st = ws + WS_STATS + vh * 64;
    float mean = st[c] * (1.0f / CNT_BN);
    float var = st[32 + c] * (1.0f / CNT_BN) - mean * mean;
    float g = vh ? gh[c] : gv[c];
    float b = vh ? bh[c] : bv[c];
    float scale = g * rsqrtf(var + 1e-5f);
    float* bn = ws + WS_BN + vh * 64;
    bn[c] = scale;
    bn[32 + c] = b - mean * scale;
}

// ---------------- BN apply in-place on v/h channels of out ----------------
__global__ __launch_bounds__(256) void k_apply(float* __restrict__ out,
                                               const float* __restrict__ ws) {
    int sch = blockIdx.x;   // 0..63
    int n = blockIdx.y;     // 0..7
    int vh = sch >> 5, oc = sch & 31;
    int ci = 64 + sch;
    int co = ((ci & 15) << 3) | (ci >> 4);
    const float* bn = ws + WS_BN + vh * 64;
    float scale = bn[oc], shift = bn[32 + oc];
    float4* p = (float4*)(out + (size_t)(n * 128 + co) * PLANE);
    for (int i = threadIdx.x; i < PLANE / 4; i += 256) {
        float4 v = p[i];
        v.x = v.x * scale + shift;
        v.y = v.y * scale + shift;
        v.z = v.z * scale + shift;
        v.w = v.w * scale + shift;
        p[i] = v;
    }
}

extern "C" void kernel_launch(void* const* d_in, const int* in_sizes, int n_in,
                              void* d_out, int out_size, void* d_ws, size_t ws_size,
                              hipStream_t stream) {
    const float* x    = (const float*)d_in[0];
    const float* sq_w = (const float*)d_in[1];
    const float* sq_b = (const float*)d_in[2];
    const float* aw_v = (const float*)d_in[3];
    const float* ab_v = (const float*)d_in[4];
    const float* w_v  = (const float*)d_in[5];
    const float* gv   = (const float*)d_in[6];
    const float* bv   = (const float*)d_in[7];
    const float* aw_h = (const float*)d_in[8];
    const float* ab_h = (const float*)d_in[9];
    const float* w_h  = (const float*)d_in[10];
    const float* gh   = (const float*)d_in[11];
    const float* bh   = (const float*)d_in[12];
    float* out = (float*)d_out;
    float* ws = (float*)d_ws;

    hipLaunchKernelGGL(k_zero, dim3(1), dim3(256), 0, stream, ws);
    hipLaunchKernelGGL(k_means, dim3(512, 4), dim3(256), 0, stream, x, ws);
    hipLaunchKernelGGL(k_agg, dim3(8), dim3(256), 0, stream,
                       aw_v, ab_v, w_v, aw_h, ab_h, w_h, ws);
    hipLaunchKernelGGL(k_cvtw, dim3(144), dim3(256), 0, stream, sq_w, ws);
    hipLaunchKernelGGL(k_vert, dim3(96, 8), dim3(192), 0, stream, x, ws, out);
    hipLaunchKernelGGL(k_horz, dim3(96, 8), dim3(192), 0, stream, x, ws, out);
    hipLaunchKernelGGL(k_stats, dim3(64, 8), dim3(256), 0, stream, out, ws);
    hipLaunchKernelGGL(k_bnfin, dim3(1), dim3(64), 0, stream, gv, bv, gh, bh, ws);
    hipLaunchKernelGGL(k_apply, dim3(64, 8), dim3(256), 0, stream, out, ws);
    hipLaunchKernelGGL(k_sq, dim3(2, 96, 8), dim3(192), 0, stream, x, sq_b, ws, out);
}

// Round 6
// 932.187 us; speedup vs baseline: 2.7210x; 2.2885x over previous
//
#include <hip/hip_runtime.h>

// ---- problem constants ----
#define NB    8
#define HIN   384
#define WIN   384
#define HOUT  192
#define WOUT  192
#define HW_IN (HIN * WIN)          // 147456
#define PLANE (HOUT * WOUT)        // 36864
#define CNT_BN (NB * HOUT * WOUT)  // 294912

// ---- workspace layout (float offsets) ----
#define WS_MEANS 0       // 512:   per-(n,c) spatial SUMS (scaled in k_agg), n*64+c
#define WS_AGGV  512     // 24576: aggregated vert weights [n][c][t][o]
#define WS_AGGH  25088   // 24576: aggregated horz weights [n][c][t][o]
#define WS_SQW   49664   // 36864: sq weights transposed [c][ky][kx][oc]
#define WS_STATS 86528   // 128:   sum_v[32] sumsq_v[32] sum_h[32] sumsq_h[32]
#define WS_BN    86656   // 128:   scale_v[32] shift_v[32] scale_h[32] shift_h[32]

// ---------------- zero means + stats ----------------
__global__ void k_zero(float* __restrict__ ws) {
    for (int i = threadIdx.x; i < 512; i += 256) ws[WS_MEANS + i] = 0.f;
    if (threadIdx.x < 128) ws[WS_STATS + threadIdx.x] = 0.f;
}

// ---------------- per-(n,c) spatial sum (4 partial blocks per plane) ----------------
__global__ __launch_bounds__(256) void k_means(const float* __restrict__ x,
                                               float* __restrict__ ws) {
    int bc = blockIdx.x;    // n*64 + c, 512
    int part = blockIdx.y;  // 0..3
    const float4* p = (const float4*)(x + (size_t)bc * HW_IN) + part * (HW_IN / 16);
    float s = 0.f;
    for (int i = threadIdx.x; i < HW_IN / 16; i += 256) {
        float4 v = p[i];
        s += (v.x + v.y) + (v.z + v.w);
    }
    __shared__ float red[256];
    red[threadIdx.x] = s;
    __syncthreads();
    for (int off = 128; off > 0; off >>= 1) {
        if ((int)threadIdx.x < off) red[threadIdx.x] += red[threadIdx.x + off];
        __syncthreads();
    }
    if (threadIdx.x == 0) atomicAdd(&ws[WS_MEANS + bc], red[0]);
}

// ---------------- attention + expert aggregation ----------------
__global__ void k_agg(const float* __restrict__ aw_v, const float* __restrict__ ab_v,
                      const float* __restrict__ wv,
                      const float* __restrict__ aw_h, const float* __restrict__ ab_h,
                      const float* __restrict__ wh, float* __restrict__ ws) {
    int n = blockIdx.x;  // 8 blocks
    __shared__ float att[8];  // [0..3] vert, [4..7] horz
    if (threadIdx.x < 8) {
        int k = threadIdx.x & 3;
        int hsel = threadIdx.x >> 2;
        const float* m = ws + WS_MEANS + n * 64 + hsel * 32;  // raw sums
        const float* aw = hsel ? aw_h : aw_v;
        const float* ab = hsel ? ab_h : ab_v;
        float dot = 0.f;
        for (int c = 0; c < 32; c++) dot += m[c] * aw[k * 32 + c];
        float z = ab[k] + dot * (1.0f / HW_IN);
        att[threadIdx.x] = 1.0f / (1.0f + expf(-z));
    }
    __syncthreads();
    // dst [c][t][o]: i = (c*3+t)*32 + o ; src [k][o][c][t] = (k*32+o)*96 + (c*3+t)
    for (int i = threadIdx.x; i < 3072; i += 256) {
        int o = i & 31;
        int r = i >> 5;  // c*3 + t
        float sv = 0.f, sh = 0.f;
#pragma unroll
        for (int k = 0; k < 4; k++) {
            sv += att[k]     * wv[(k * 32 + o) * 96 + r];
            sh += att[4 + k] * wh[(k * 32 + o) * 96 + r];
        }
        ws[WS_AGGV + n * 3072 + i] = sv;
        ws[WS_AGGH + n * 3072 + i] = sh;
    }
}

// ---------------- sq weight transpose: [oc][c][ky][kx] -> [c][ky][kx][oc] ----------------
__global__ void k_cvtw(const float* __restrict__ sq_w, float* __restrict__ ws) {
    int i = blockIdx.x * 256 + threadIdx.x;  // 36864 total, grid 144
    int oc = i & 63;
    int r = i >> 6;           // c*9 + (ky*3+kx)
    int c = r / 9, q = r % 9;
    ws[WS_SQW + i] = sq_w[(oc * 64 + c) * 9 + q];
}

// ---------------- square 3x3/s2 conv: ALL 64 oc per thread, one out row per block --------
// (exact R2 structure: measured 339 us, VGPR 44, clean codegen)
__global__ __launch_bounds__(192) void k_sq(const float* __restrict__ x,
                                            const float* __restrict__ sq_b,
                                            const float* __restrict__ ws,
                                            float* __restrict__ out) {
    int xo = threadIdx.x;   // 0..191
    int yo = blockIdx.x;    // 0..191
    int n  = blockIdx.y;    // 0..7
    const float* wp = ws + WS_SQW;
    float acc[64];
#pragma unroll
    for (int j = 0; j < 64; j++) acc[j] = sq_b[j];
    const float* xb = x + (size_t)n * 64 * HW_IN;
    int c2 = 2 * xo;
    int iy0 = 2 * yo - 1;
    for (int c = 0; c < 64; c++) {
        const float* xc = xb + (size_t)c * HW_IN;
        float v[9];
#pragma unroll
        for (int ky = 0; ky < 3; ky++) {
            int iy = iy0 + ky;   // wave-uniform (yo from blockIdx)
            if (iy >= 0) {
                const float* row = xc + (size_t)iy * WIN;
                float2 v12 = *(const float2*)(row + c2);
                v[ky * 3 + 0] = (xo > 0) ? row[c2 - 1] : 0.f;
                v[ky * 3 + 1] = v12.x;
                v[ky * 3 + 2] = v12.y;
            } else {
                v[ky * 3 + 0] = v[ky * 3 + 1] = v[ky * 3 + 2] = 0.f;
            }
        }
        const float* wc = wp + c * 576;   // [ky][kx][64] — wave-uniform -> s_load
#pragma unroll
        for (int t = 0; t < 9; t++) {
            float vv = v[t];
#pragma unroll
            for (int j = 0; j < 64; j++) acc[j] += vv * wc[t * 64 + j];
        }
    }
    size_t ob = (size_t)n * 128 * PLANE + (size_t)yo * WOUT + xo;
#pragma unroll
    for (int j = 0; j < 64; j++) {
        int co = ((j & 15) << 3) | (j >> 4);   // channel shuffle g=8 (ci = j)
        out[ob + (size_t)co * PLANE] = acc[j];
    }
}

// ---------------- vertical CondConv 3x1 pad(1,0): 32 oc x 2 cols, single acc[64] --------
// block 192 = 2 rows x 96 col-pairs; per c: 3 float4 loads -> 192 FMA
__global__ __launch_bounds__(192) void k_vert(const float* __restrict__ x,
                                              const float* __restrict__ ws,
                                              float* __restrict__ out) {
    int tid = threadIdx.x;
    int i = tid % 96;
    int r = tid / 96;
    int yo = blockIdx.x * 2 + r;   // grid.x = 96
    int n  = blockIdx.y;
    const float* wn = ws + WS_AGGV + n * 3072;
    float acc[64];                 // [j] = out col 2i, [32+j] = out col 2i+1
#pragma unroll
    for (int j = 0; j < 64; j++) acc[j] = 0.f;
    const float* xb = x + (size_t)n * 64 * HW_IN;   // channels 0..31
    int c4 = 4 * i;
    int iy0 = 2 * yo - 1;
    for (int c = 0; c < 32; c++) {
        const float* xc = xb + (size_t)c * HW_IN;
        float4 vv[3];
#pragma unroll
        for (int t = 0; t < 3; t++) {
            int iy = iy0 + t;
            const float* row = xc + (size_t)iy * WIN + c4;
            vv[t] = (iy >= 0) ? *(const float4*)row : make_float4(0.f, 0.f, 0.f, 0.f);
        }
#pragma unroll
        for (int t = 0; t < 3; t++) {
            const float* wr = wn + (c * 3 + t) * 32;   // wave-uniform -> s_load
            float va = vv[t].x, vb = vv[t].z;          // input cols 4i, 4i+2
#pragma unroll
            for (int j = 0; j < 32; j++) {
                float w = wr[j];
                acc[j]      += va * w;
                acc[32 + j] += vb * w;
            }
        }
    }
    size_t ob = (size_t)n * 128 * PLANE + (size_t)yo * WOUT + 2 * i;
#pragma unroll
    for (int j = 0; j < 32; j++) {
        int ci = 64 + j;
        int co = ((ci & 15) << 3) | (ci >> 4);
        out[ob + (size_t)co * PLANE]     = acc[j];
        out[ob + (size_t)co * PLANE + 1] = acc[32 + j];
    }
}

// ---------------- horizontal CondConv 1x3 pad(0,1): 32 oc x 2 cols, single acc[64] ------
__global__ __launch_bounds__(192) void k_horz(const float* __restrict__ x,
                                              const float* __restrict__ ws,
                                              float* __restrict__ out) {
    int tid = threadIdx.x;
    int i = tid % 96;
    int r = tid / 96;
    int yo = blockIdx.x * 2 + r;   // grid.x = 96
    int n  = blockIdx.y;
    const float* wn = ws + WS_AGGH + n * 3072;
    float acc[64];                 // [j] = out col 2i, [32+j] = out col 2i+1
#pragma unroll
    for (int j = 0; j < 64; j++) acc[j] = 0.f;
    const float* xb = x + ((size_t)n * 64 + 32) * HW_IN;   // channels 32..63
    int c4 = 4 * i;
    for (int c = 0; c < 32; c++) {
        const float* row = xb + (size_t)c * HW_IN + (size_t)(2 * yo) * WIN + c4;
        float4 v = *(const float4*)row;          // cols 4i..4i+3
        float vm1 = (i > 0) ? row[-1] : 0.f;     // col 4i-1
        const float* wr = wn + c * 96;           // wave-uniform -> s_load
#pragma unroll
        for (int j = 0; j < 32; j++) {
            float w0 = wr[j], w1 = wr[32 + j], w2 = wr[64 + j];
            acc[j]      += vm1 * w0 + v.x * w1 + v.y * w2;
            acc[32 + j] += v.y * w0 + v.z * w1 + v.w * w2;
        }
    }
    size_t ob = (size_t)n * 128 * PLANE + (size_t)yo * WOUT + 2 * i;
#pragma unroll
    for (int j = 0; j < 32; j++) {
        int ci = 96 + j;
        int co = ((ci & 15) << 3) | (ci >> 4);
        out[ob + (size_t)co * PLANE]     = acc[j];
        out[ob + (size_t)co * PLANE + 1] = acc[32 + j];
    }
}

// ---------------- BN stats over raw conv output (v/h channels of out) ----------------
__global__ __launch_bounds__(256) void k_stats(const float* __restrict__ out,
                                               float* __restrict__ ws) {
    int sch = blockIdx.x;   // 0..63: 0..31 vert oc, 32..63 horz oc
    int n = blockIdx.y;     // 0..7
    int vh = sch >> 5, oc = sch & 31;
    int ci = 64 + sch;
    int co = ((ci & 15) << 3) | (ci >> 4);
    const float4* p = (const float4*)(out + (size_t)(n * 128 + co) * PLANE);
    float s = 0.f, q = 0.f;
    for (int i = threadIdx.x; i < PLANE / 4; i += 256) {
        float4 v = p[i];
        s += (v.x + v.y) + (v.z + v.w);
        q += (v.x * v.x + v.y * v.y) + (v.z * v.z + v.w * v.w);
    }
    __shared__ float rs[256], rq[256];
    rs[threadIdx.x] = s; rq[threadIdx.x] = q;
    __syncthreads();
    for (int off = 128; off > 0; off >>= 1) {
        if ((int)threadIdx.x < off) {
            rs[threadIdx.x] += rs[threadIdx.x + off];
            rq[threadIdx.x] += rq[threadIdx.x + off];
        }
        __syncthreads();
    }
    if (threadIdx.x == 0) {
        atomicAdd(&ws[WS_STATS + vh * 64 + oc], rs[0]);
        atomicAdd(&ws[WS_STATS + vh * 64 + 32 + oc], rq[0]);
    }
}

// ---------------- BN finalize ----------------
__global__ void k_bnfin(const float* __restrict__ gv, const float* __restrict__ bv,
                        const float* __restrict__ gh, const float* __restrict__ bh,
                        float* __restrict__ ws) {
    int t = threadIdx.x;
    if (t >= 64) return;
    int vh = t >> 5;  // 0 = vert, 1 = horz
    int c = t & 31;
    const float* st = ws + WS_STATS + vh * 64;
    float mean = st[c] * (1.0f / CNT_BN);
    float var = st[32 + c] * (1.0f / CNT_BN) - mean * mean;
    float g = vh ? gh[c] : gv[c];
    float b = vh ? bh[c] : bv[c];
    float scale = g * rsqrtf(var + 1e-5f);
    float* bn = ws + WS_BN + vh * 64;
    bn[c] = scale;
    bn[32 + c] = b - mean * scale;
}

// ---------------- BN apply in-place on v/h channels of out ----------------
__global__ __launch_bounds__(256) void k_apply(float* __restrict__ out,
                                               const float* __restrict__ ws) {
    int sch = blockIdx.x;   // 0..63
    int n = blockIdx.y;     // 0..7
    int vh = sch >> 5, oc = sch & 31;
    int ci = 64 + sch;
    int co = ((ci & 15) << 3) | (ci >> 4);
    const float* bn = ws + WS_BN + vh * 64;
    float scale = bn[oc], shift = bn[32 + oc];
    float4* p = (float4*)(out + (size_t)(n * 128 + co) * PLANE);
    for (int i = threadIdx.x; i < PLANE / 4; i += 256) {
        float4 v = p[i];
        v.x = v.x * scale + shift;
        v.y = v.y * scale + shift;
        v.z = v.z * scale + shift;
        v.w = v.w * scale + shift;
        p[i] = v;
    }
}

extern "C" void kernel_launch(void* const* d_in, const int* in_sizes, int n_in,
                              void* d_out, int out_size, void* d_ws, size_t ws_size,
                              hipStream_t stream) {
    const float* x    = (const float*)d_in[0];
    const float* sq_w = (const float*)d_in[1];
    const float* sq_b = (const float*)d_in[2];
    const float* aw_v = (const float*)d_in[3];
    const float* ab_v = (const float*)d_in[4];
    const float* w_v  = (const float*)d_in[5];
    const float* gv   = (const float*)d_in[6];
    const float* bv   = (const float*)d_in[7];
    const float* aw_h = (const float*)d_in[8];
    const float* ab_h = (const float*)d_in[9];
    const float* w_h  = (const float*)d_in[10];
    const float* gh   = (const float*)d_in[11];
    const float* bh   = (const float*)d_in[12];
    float* out = (float*)d_out;
    float* ws = (float*)d_ws;

    hipLaunchKernelGGL(k_zero, dim3(1), dim3(256), 0, stream, ws);
    hipLaunchKernelGGL(k_means, dim3(512, 4), dim3(256), 0, stream, x, ws);
    hipLaunchKernelGGL(k_agg, dim3(8), dim3(256), 0, stream,
                       aw_v, ab_v, w_v, aw_h, ab_h, w_h, ws);
    hipLaunchKernelGGL(k_cvtw, dim3(144), dim3(256), 0, stream, sq_w, ws);
    hipLaunchKernelGGL(k_vert, dim3(96, 8), dim3(192), 0, stream, x, ws, out);
    hipLaunchKernelGGL(k_horz, dim3(96, 8), dim3(192), 0, stream, x, ws, out);
    hipLaunchKernelGGL(k_stats, dim3(64, 8), dim3(256), 0, stream, out, ws);
    hipLaunchKernelGGL(k_bnfin, dim3(1), dim3(64), 0, stream, gv, bv, gh, bh, ws);
    hipLaunchKernelGGL(k_apply, dim3(64, 8), dim3(256), 0, stream, out, ws);
    hipLaunchKernelGGL(k_sq, dim3(192, 8), dim3(192), 0, stream, x, sq_b, ws, out);
}